// Round 1
// baseline (132.709 us; speedup 1.0000x reference)
//
#include <hip/hip_runtime.h>
#include <hip/hip_cooperative_groups.h>
#include <cmath>

// Diagonal linear recurrence y[l][h] = exp(tau[h])*y[l-1][h] + x[l][h]
// L=16384, H=1024, fp32.
//
// R8: single-pass decoupled lookback. R7's coop kernel spent ~100us in two
// 1024-block grid.sync()s (VALUBusy 1.8%, HBM 6% of peak -- pure waiting).
// Replace them with point-to-point flags:
//   every block:  chunk scan in regs, post e_c (+flag)
//   rep (r=P-1):  gather 16 partition ends -> post a_p (+flag)
//                 gather a_0..a_{p-1}       -> post Qc_p (+flag)
//   every block:  overlap in-partition prefix w with waiting,
//                 carry = T^r o Qc_p + w, apply, nt-store y.
// Sync chain = 3 flag hops over <=64KB instead of 2 full-grid barriers; the
// 960-blocks-idle phase-2 and the per-block 63-entry carry re-scan disappear.
// All 1024 blocks co-resident (4/CU, checked at launch) -> spins are safe;
// reps wait only on lower block IDs, normal blocks wait <=15 IDs ahead.
// Flags zeroed per-launch by hipMemsetAsync (graph-capturable).
// Fallbacks: R7 coop kernel, then R6 feed-forward 4-kernel path.

namespace cg = cooperative_groups;

static constexpr int TC = 16;    // rows per chunk      -> C  = 1024
static constexpr int P  = 16;    // chunks per partition-> NP = 64
static constexpr int FS = 32;    // flag stride in uints = 128B (one L2 line)

typedef float nt4 __attribute__((ext_vector_type(4)));

__device__ inline float4 ntload(const float4* p) {
    nt4 v = __builtin_nontemporal_load((const nt4*)p);
    return make_float4(v.x, v.y, v.z, v.w);
}

__device__ inline unsigned ld_flag(unsigned* p) {
    return __hip_atomic_load(p, __ATOMIC_RELAXED, __HIP_MEMORY_SCOPE_AGENT);
}
__device__ inline void st_flag(unsigned* p, unsigned v) {
    __hip_atomic_store(p, v, __ATOMIC_RELEASE, __HIP_MEMORY_SCOPE_AGENT);
}

__global__ __launch_bounds__(256, 4)   // keep unified regs <=128 -> 4 blocks/CU
void li_lookback(const float4* __restrict__ xv, const float4* __restrict__ tauv,
                 float4* __restrict__ yv, float4* __restrict__ ends,
                 float4* __restrict__ pagg, float4* __restrict__ qc,
                 unsigned* __restrict__ eflag, unsigned* __restrict__ aflag,
                 unsigned* __restrict__ qflag, int HV)
{
    const int t = threadIdx.x;           // float4 column (4 channels)
    const int c = blockIdx.x;            // chunk
    const int p = c / P;                 // partition
    const int r = c % P;                 // chunk within partition

    const float4 tv = tauv[t];
    const float lx = expf(tv.x), ly = expf(tv.y),
                lz = expf(tv.z), lw = expf(tv.w);
    const float Tx = expf(tv.x * (float)TC), Ty = expf(tv.y * (float)TC),
                Tz = expf(tv.z * (float)TC), Tw = expf(tv.w * (float)TC);

    // ---- phase 1: chunk into registers, local zero-carry scan ----
    const size_t base = (size_t)c * TC * HV + t;
    float4 buf[TC];
#pragma unroll
    for (int i = 0; i < TC; ++i)
        buf[i] = ntload(&xv[base + (size_t)i * HV]);

    float4 s = make_float4(0.f, 0.f, 0.f, 0.f);
#pragma unroll
    for (int i = 0; i < TC; ++i) {
        s.x = fmaf(lx, s.x, buf[i].x);
        s.y = fmaf(ly, s.y, buf[i].y);
        s.z = fmaf(lz, s.z, buf[i].z);
        s.w = fmaf(lw, s.w, buf[i].w);
        buf[i] = s;
    }
    ends[(size_t)c * HV + t] = s;
    __threadfence();                      // drain + make device-visible
    __syncthreads();
    if (t == 0) st_flag(&eflag[(size_t)c * FS], 1u);

    // ---- in-partition exclusive prefix w over e_{p*P}..e_{p*P+r-1} ----
    if (t < r) {
        while (ld_flag(&eflag[(size_t)(p * P + t) * FS]) == 0u)
            __builtin_amdgcn_s_sleep(1);
    }
    __syncthreads();
    __threadfence();                      // acquire: invalidate stale lines

    float4 w = make_float4(0.f, 0.f, 0.f, 0.f);
    const float4* ep = ends + (size_t)p * P * HV + t;
    for (int j0 = 0; j0 < r; j0 += 4) {
        float4 v[4];
#pragma unroll
        for (int j = 0; j < 4; ++j)
            if (j0 + j < r) v[j] = ep[(size_t)(j0 + j) * HV];
#pragma unroll
        for (int j = 0; j < 4; ++j) {
            if (j0 + j < r) {
                w.x = fmaf(Tx, w.x, v[j].x);
                w.y = fmaf(Ty, w.y, v[j].y);
                w.z = fmaf(Tz, w.z, v[j].z);
                w.w = fmaf(Tw, w.w, v[j].w);
            }
        }
    }

    float4 cc;                            // carry into this chunk
    const float fr = (float)(TC * r);
    if (r == P - 1) {
        // ---- partition rep: aggregate a_p = T o w + s ----
        float4 a;
        a.x = fmaf(Tx, w.x, s.x);
        a.y = fmaf(Ty, w.y, s.y);
        a.z = fmaf(Tz, w.z, s.z);
        a.w = fmaf(Tw, w.w, s.w);
        pagg[(size_t)p * HV + t] = a;
        __threadfence();
        __syncthreads();
        if (t == 0) st_flag(&aflag[(size_t)p * FS], 1u);

        // ---- cross-partition carry Qc_p = scan(a_0..a_{p-1}) ----
        if (t < p) {
            while (ld_flag(&aflag[(size_t)t * FS]) == 0u)
                __builtin_amdgcn_s_sleep(1);
        }
        __syncthreads();
        __threadfence();

        const float fQ = (float)(TC * P);
        const float Qx = expf(tv.x * fQ), Qy = expf(tv.y * fQ),
                    Qz = expf(tv.z * fQ), Qw = expf(tv.w * fQ);
        float4 carry = make_float4(0.f, 0.f, 0.f, 0.f);
        for (int q0 = 0; q0 < p; q0 += 4) {
            float4 v[4];
#pragma unroll
            for (int j = 0; j < 4; ++j)
                if (q0 + j < p) v[j] = pagg[(size_t)(q0 + j) * HV + t];
#pragma unroll
            for (int j = 0; j < 4; ++j) {
                if (q0 + j < p) {
                    carry.x = fmaf(Qx, carry.x, v[j].x);
                    carry.y = fmaf(Qy, carry.y, v[j].y);
                    carry.z = fmaf(Qz, carry.z, v[j].z);
                    carry.w = fmaf(Qw, carry.w, v[j].w);
                }
            }
        }
        qc[(size_t)p * HV + t] = carry;
        __threadfence();
        __syncthreads();
        if (t == 0) st_flag(&qflag[(size_t)p * FS], 1u);

        const float Rx = expf(tv.x * fr), Ry = expf(tv.y * fr),
                    Rz = expf(tv.z * fr), Rw = expf(tv.w * fr);
        cc.x = fmaf(Rx, carry.x, w.x);
        cc.y = fmaf(Ry, carry.y, w.y);
        cc.z = fmaf(Rz, carry.z, w.z);
        cc.w = fmaf(Rw, carry.w, w.w);
    } else {
        // ---- normal block: wait for partition carry, one FMA ----
        if (t == 0) {
            while (ld_flag(&qflag[(size_t)p * FS]) == 0u)
                __builtin_amdgcn_s_sleep(1);
        }
        __syncthreads();
        __threadfence();
        const float4 qv = qc[(size_t)p * HV + t];
        const float Rx = expf(tv.x * fr), Ry = expf(tv.y * fr),
                    Rz = expf(tv.z * fr), Rw = expf(tv.w * fr);
        cc.x = fmaf(Rx, qv.x, w.x);
        cc.y = fmaf(Ry, qv.y, w.y);
        cc.z = fmaf(Rz, qv.z, w.z);
        cc.w = fmaf(Rw, qv.w, w.w);
    }

    // ---- epilogue: apply carry, nt-store y ----
    float4 pm = make_float4(lx, ly, lz, lw);
    nt4* yn = (nt4*)yv;
#pragma unroll
    for (int i = 0; i < TC; ++i) {
        nt4 o = { fmaf(pm.x, cc.x, buf[i].x),
                  fmaf(pm.y, cc.y, buf[i].y),
                  fmaf(pm.z, cc.z, buf[i].z),
                  fmaf(pm.w, cc.w, buf[i].w) };
        __builtin_nontemporal_store(o, &yn[base + (size_t)i * HV]);
        pm.x *= lx; pm.y *= ly; pm.z *= lz; pm.w *= lw;
    }
}

// ---------------- R7 cooperative fallback ----------------

__global__ __launch_bounds__(256, 4)
void li_coop(const float4* __restrict__ xv, const float4* __restrict__ tauv,
             float4* __restrict__ yv, float4* __restrict__ ends,
             float4* __restrict__ pa, int HV, int NP)
{
    const int t = threadIdx.x;
    const int c = blockIdx.x;

    const float4 tv = tauv[t];
    const float lx = expf(tv.x), ly = expf(tv.y),
                lz = expf(tv.z), lw = expf(tv.w);
    const float Tx = expf(tv.x * (float)TC), Ty = expf(tv.y * (float)TC),
                Tz = expf(tv.z * (float)TC), Tw = expf(tv.w * (float)TC);
    const float fQ = (float)(TC * P);
    const float Qx = expf(tv.x * fQ), Qy = expf(tv.y * fQ),
                Qz = expf(tv.z * fQ), Qw = expf(tv.w * fQ);

    const size_t base = (size_t)c * TC * HV + t;
    float4 buf[TC];
#pragma unroll
    for (int i = 0; i < TC; ++i)
        buf[i] = ntload(&xv[base + (size_t)i * HV]);

    float4 s = make_float4(0.f, 0.f, 0.f, 0.f);
#pragma unroll
    for (int i = 0; i < TC; ++i) {
        s.x = fmaf(lx, s.x, buf[i].x);
        s.y = fmaf(ly, s.y, buf[i].y);
        s.z = fmaf(lz, s.z, buf[i].z);
        s.w = fmaf(lw, s.w, buf[i].w);
        buf[i] = s;
    }
    ends[(size_t)c * HV + t] = s;

    cg::this_grid().sync();

    if (c < NP) {
        const float4* ep = ends + (size_t)c * P * HV + t;
        float4 a = make_float4(0.f, 0.f, 0.f, 0.f);
#pragma unroll
        for (int j0 = 0; j0 < P; j0 += 8) {
            float4 v[8];
#pragma unroll
            for (int j = 0; j < 8; ++j)
                v[j] = ep[(size_t)(j0 + j) * HV];
#pragma unroll
            for (int j = 0; j < 8; ++j) {
                a.x = fmaf(Tx, a.x, v[j].x);
                a.y = fmaf(Ty, a.y, v[j].y);
                a.z = fmaf(Tz, a.z, v[j].z);
                a.w = fmaf(Tw, a.w, v[j].w);
            }
        }
        pa[(size_t)c * HV + t] = a;
    }

    cg::this_grid().sync();

    const int p = c / P;
    const int r = c % P;

    float4 carry = make_float4(0.f, 0.f, 0.f, 0.f);
    for (int q0 = 0; q0 < p; q0 += 8) {
        const int n = p - q0;
        float4 v[8];
#pragma unroll
        for (int j = 0; j < 8; ++j)
            if (j < n) v[j] = pa[(size_t)(q0 + j) * HV + t];
#pragma unroll
        for (int j = 0; j < 8; ++j) {
            if (j < n) {
                carry.x = fmaf(Qx, carry.x, v[j].x);
                carry.y = fmaf(Qy, carry.y, v[j].y);
                carry.z = fmaf(Qz, carry.z, v[j].z);
                carry.w = fmaf(Qw, carry.w, v[j].w);
            }
        }
    }
    {
        const float4* ep = ends + (size_t)p * P * HV + t;
        for (int j0 = 0; j0 < r; j0 += 8) {
            const int n = r - j0;
            float4 v[8];
#pragma unroll
            for (int j = 0; j < 8; ++j)
                if (j < n) v[j] = ep[(size_t)(j0 + j) * HV];
#pragma unroll
            for (int j = 0; j < 8; ++j) {
                if (j < n) {
                    carry.x = fmaf(Tx, carry.x, v[j].x);
                    carry.y = fmaf(Ty, carry.y, v[j].y);
                    carry.z = fmaf(Tz, carry.z, v[j].z);
                    carry.w = fmaf(Tw, carry.w, v[j].w);
                }
            }
        }
    }

    float4 pm = make_float4(lx, ly, lz, lw);
    nt4* yn = (nt4*)yv;
#pragma unroll
    for (int i = 0; i < TC; ++i) {
        nt4 o = { fmaf(pm.x, carry.x, buf[i].x),
                  fmaf(pm.y, carry.y, buf[i].y),
                  fmaf(pm.z, carry.z, buf[i].z),
                  fmaf(pm.w, carry.w, buf[i].w) };
        __builtin_nontemporal_store(o, &yn[base + (size_t)i * HV]);
        pm.x *= lx; pm.y *= ly; pm.z *= lz; pm.w *= lw;
    }
}

// ---------------- R6 feed-forward fallback ----------------

__global__ __launch_bounds__(256)
void li_ends(const float4* __restrict__ xv, const float4* __restrict__ tauv,
             float4* __restrict__ ends, int HV) {
    const int t = threadIdx.x;
    const int c = blockIdx.x;
    const float4 tv = tauv[t];
    const float lx = expf(tv.x), ly = expf(tv.y),
                lz = expf(tv.z), lw = expf(tv.w);
    const float4* xp = xv + (size_t)c * TC * HV + t;
    float4 buf[TC];
#pragma unroll
    for (int i = 0; i < TC; ++i)
        buf[i] = xp[(size_t)i * HV];
    float4 s = make_float4(0.f, 0.f, 0.f, 0.f);
#pragma unroll
    for (int i = 0; i < TC; ++i) {
        s.x = fmaf(lx, s.x, buf[i].x);
        s.y = fmaf(ly, s.y, buf[i].y);
        s.z = fmaf(lz, s.z, buf[i].z);
        s.w = fmaf(lw, s.w, buf[i].w);
    }
    ends[(size_t)c * HV + t] = s;
}

__global__ __launch_bounds__(256)
void li_pagg(const float4* __restrict__ ends, const float4* __restrict__ tauv,
             float4* __restrict__ pa, int HV) {
    const int gid = blockIdx.x * 256 + threadIdx.x;
    const int t = gid % HV;
    const int p = gid / HV;
    const float4 tv = tauv[t];
    const float Tx = expf(tv.x * (float)TC), Ty = expf(tv.y * (float)TC),
                Tz = expf(tv.z * (float)TC), Tw = expf(tv.w * (float)TC);
    const float4* ep = ends + (size_t)p * P * HV + t;
    float4 buf[P];
#pragma unroll
    for (int j = 0; j < P; ++j)
        buf[j] = ep[(size_t)j * HV];
    float4 s = make_float4(0.f, 0.f, 0.f, 0.f);
#pragma unroll
    for (int j = 0; j < P; ++j) {
        s.x = fmaf(Tx, s.x, buf[j].x);
        s.y = fmaf(Ty, s.y, buf[j].y);
        s.z = fmaf(Tz, s.z, buf[j].z);
        s.w = fmaf(Tw, s.w, buf[j].w);
    }
    pa[(size_t)p * HV + t] = s;
}

__global__ __launch_bounds__(256)
void li_pscan(float4* __restrict__ pa, const float4* __restrict__ tauv,
              int HV, int NP) {
    const int t = threadIdx.x;
    const float4 tv = tauv[t];
    const float fP = (float)(P * TC);
    const float Px = expf(tv.x * fP), Py = expf(tv.y * fP),
                Pz = expf(tv.z * fP), Pw = expf(tv.w * fP);
    float4 c = make_float4(0.f, 0.f, 0.f, 0.f);
    for (int p0 = 0; p0 < NP; p0 += 16) {
        float4 v[16];
#pragma unroll
        for (int j = 0; j < 16; ++j)
            v[j] = pa[(size_t)(p0 + j) * HV + t];
#pragma unroll
        for (int j = 0; j < 16; ++j) {
            const float4 a = v[j];
            v[j] = c;
            c.x = fmaf(Px, c.x, a.x);
            c.y = fmaf(Py, c.y, a.y);
            c.z = fmaf(Pz, c.z, a.z);
            c.w = fmaf(Pw, c.w, a.w);
        }
#pragma unroll
        for (int j = 0; j < 16; ++j)
            pa[(size_t)(p0 + j) * HV + t] = v[j];
    }
}

__global__ __launch_bounds__(256)
void li_out(const float4* __restrict__ xv, const float4* __restrict__ tauv,
            const float4* __restrict__ ends, const float4* __restrict__ pc,
            float4* __restrict__ yv, int HV) {
    const int t = threadIdx.x;
    const int c = blockIdx.x;
    const int p = c / P;
    const int r = c % P;
    const float4 tv = tauv[t];
    const float lx = expf(tv.x), ly = expf(tv.y),
                lz = expf(tv.z), lw = expf(tv.w);
    const float Tx = expf(tv.x * (float)TC), Ty = expf(tv.y * (float)TC),
                Tz = expf(tv.z * (float)TC), Tw = expf(tv.w * (float)TC);
    float4 carry = pc[(size_t)p * HV + t];
    {
        float4 v[P - 1];
        const float4* ep = ends + (size_t)p * P * HV + t;
#pragma unroll
        for (int j = 0; j < P - 1; ++j)
            if (j < r) v[j] = ep[(size_t)j * HV];
#pragma unroll
        for (int j = 0; j < P - 1; ++j) {
            if (j < r) {
                carry.x = fmaf(Tx, carry.x, v[j].x);
                carry.y = fmaf(Ty, carry.y, v[j].y);
                carry.z = fmaf(Tz, carry.z, v[j].z);
                carry.w = fmaf(Tw, carry.w, v[j].w);
            }
        }
    }
    const size_t base = (size_t)c * TC * HV + t;
    float4 buf[TC];
#pragma unroll
    for (int i = 0; i < TC; ++i)
        buf[i] = xv[base + (size_t)i * HV];
    float4 s = carry;
#pragma unroll
    for (int i = 0; i < TC; ++i) {
        s.x = fmaf(lx, s.x, buf[i].x);
        s.y = fmaf(ly, s.y, buf[i].y);
        s.z = fmaf(lz, s.z, buf[i].z);
        s.w = fmaf(lw, s.w, buf[i].w);
        buf[i] = s;
    }
    nt4* yn = (nt4*)yv;
#pragma unroll
    for (int i = 0; i < TC; ++i) {
        nt4 o = { buf[i].x, buf[i].y, buf[i].z, buf[i].w };
        __builtin_nontemporal_store(o, &yn[base + (size_t)i * HV]);
    }
}

extern "C" void kernel_launch(void* const* d_in, const int* in_sizes, int n_in,
                              void* d_out, int out_size, void* d_ws, size_t ws_size,
                              hipStream_t stream) {
    const float* x   = (const float*)d_in[0];
    const float* tau = (const float*)d_in[1];
    float* y = (float*)d_out;

    const int H  = in_sizes[1];        // 1024
    const int L  = in_sizes[0] / H;    // 16384
    const int C  = L / TC;             // 1024
    const int NP = C / P;              // 64
    const int HV = H / 4;              // 256 float4 columns

    float4* ends = (float4*)d_ws;                       // C*HV float4 = 4 MB
    float4* pagg = ends + (size_t)C * HV;               // NP*HV float4 = 256 KB
    float4* qc   = pagg + (size_t)NP * HV;              // NP*HV float4 = 256 KB
    unsigned* eflag = (unsigned*)(qc + (size_t)NP * HV);
    unsigned* aflag = eflag + (size_t)C * FS;
    unsigned* qflag = aflag + (size_t)NP * FS;
    const size_t flagBytes = (size_t)(C + 2 * NP) * FS * sizeof(unsigned);
    const size_t needLB = ((size_t)C * HV + 2 * (size_t)NP * HV) * sizeof(float4)
                          + flagBytes;                  // ~4.65 MB

    const float4* xv   = (const float4*)x;
    const float4* tauv = (const float4*)tau;
    float4*       yv   = (float4*)y;

    // Cached device/occupancy queries (host-side, graph-capture safe).
    static int lb_bpc = -1;
    static int nCU    = -1;
    if (lb_bpc < 0) {
        int b = 0;
        if (hipOccupancyMaxActiveBlocksPerMultiprocessor(&b, li_lookback, 256, 0)
            != hipSuccess) b = 0;
        lb_bpc = b;
        hipDeviceProp_t prop;
        int dev = 0;
        if (hipGetDevice(&dev) == hipSuccess &&
            hipGetDeviceProperties(&prop, dev) == hipSuccess)
            nCU = prop.multiProcessorCount;
        else
            nCU = 0;
    }

    // Lookback path requires full co-residency so spins can't deadlock.
    if (lb_bpc >= 4 && (size_t)lb_bpc * (size_t)nCU >= (size_t)C &&
        ws_size >= needLB) {
        hipMemsetAsync(eflag, 0, flagBytes, stream);
        li_lookback<<<dim3(C), dim3(256), 0, stream>>>(
            xv, tauv, yv, ends, pagg, qc, eflag, aflag, qflag, HV);
        return;
    }

    // R7 cooperative fallback.
    int blocksPerCU = 0;
    hipError_t qe = hipOccupancyMaxActiveBlocksPerMultiprocessor(
        &blocksPerCU, li_coop, 256, 0);
    bool coop_ok = false;
    if (qe == hipSuccess && blocksPerCU >= 4) {
        void* args[] = { (void*)&xv, (void*)&tauv, (void*)&yv,
                         (void*)&ends, (void*)&pagg, (void*)&HV, (void*)&NP };
        hipError_t le = hipLaunchCooperativeKernel(
            li_coop, dim3(C), dim3(256), args, 0u, stream);
        coop_ok = (le == hipSuccess);
    }

    if (!coop_ok) {
        li_ends <<<dim3(C),             dim3(256), 0, stream>>>(xv, tauv, ends, HV);
        li_pagg <<<dim3(NP * HV / 256), dim3(256), 0, stream>>>(ends, tauv, pagg, HV);
        li_pscan<<<dim3(1),             dim3(256), 0, stream>>>(pagg, tauv, HV, NP);
        li_out  <<<dim3(C),             dim3(256), 0, stream>>>(xv, tauv, ends, pagg,
                                                                yv, HV);
    }
}

// Round 2
// 132.142 us; speedup vs baseline: 1.0043x; 1.0043x over previous
//
#include <hip/hip_runtime.h>
#include <hip/hip_cooperative_groups.h>
#include <cmath>

// Diagonal linear recurrence y[l][h] = exp(tau[h])*y[l-1][h] + x[l][h]
// L=16384, H=1024, fp32.
//
// R9: contention-minimized lookback. R7 (grid.sync) and R8 (3-hop flag
// lookback) both time at 132us -- the sync TOPOLOGY is not the limiter.
// Both share: hot spin lines hammered by many blocks (agent-scope polls
// bypass L1 -> every poll is an L2/fabric transaction, ~hundreds GB/s of
// poll traffic concurrent with streaming), ~30MB of sibling `ends`
// re-reads, and nt loads on x that defeat LLC retention across replays.
// R9 removes all three:
//   normal block: phase1 scan, post e_c (+flag), spin on PRIVATE kflag[c]
//                 with s_sleep(8), read own 4KB carry K_c, apply, store y.
//   rep (r=15):   wait 15 sibling eflags, compute partition aggregate a_p,
//                 post; gather lower a_q -> Qc_p; iteratively publish
//                 per-chunk carries K_c = T o K_{c-1} + E_{c-1} (+flags).
// Each flag line has exactly one writer and (mostly) one poller.
// x loads are CACHED (LLC-resident across graph replays); y stores stay nt.
// Co-residency gate + R7 coop + R6 4-kernel fallbacks retained.

namespace cg = cooperative_groups;

static constexpr int TC = 16;    // rows per chunk      -> C  = 1024
static constexpr int P  = 16;    // chunks per partition-> NP = 64
static constexpr int FS = 32;    // flag stride in uints = 128B

typedef float nt4 __attribute__((ext_vector_type(4)));

__device__ inline float4 ntload(const float4* p) {
    nt4 v = __builtin_nontemporal_load((const nt4*)p);
    return make_float4(v.x, v.y, v.z, v.w);
}

__device__ inline unsigned ld_flag(unsigned* p) {
    return __hip_atomic_load(p, __ATOMIC_RELAXED, __HIP_MEMORY_SCOPE_AGENT);
}
__device__ inline void st_flag(unsigned* p, unsigned v) {
    __hip_atomic_store(p, v, __ATOMIC_RELEASE, __HIP_MEMORY_SCOPE_AGENT);
}

__global__ __launch_bounds__(256, 4)   // 4 blocks/CU -> all 1024 co-resident
void li_rep(const float4* __restrict__ xv, const float4* __restrict__ tauv,
            float4* __restrict__ yv, float4* __restrict__ ends,
            float4* __restrict__ pagg, float4* __restrict__ kc,
            unsigned* __restrict__ eflag, unsigned* __restrict__ aflag,
            unsigned* __restrict__ kflag, int HV)
{
    const int t = threadIdx.x;           // float4 column (4 channels)
    const int c = blockIdx.x;            // chunk
    const int p = c / P;                 // partition
    const int r = c % P;                 // chunk within partition

    const float4 tv = tauv[t];
    const float lx = expf(tv.x), ly = expf(tv.y),
                lz = expf(tv.z), lw = expf(tv.w);
    const float Tx = expf(tv.x * (float)TC), Ty = expf(tv.y * (float)TC),
                Tz = expf(tv.z * (float)TC), Tw = expf(tv.w * (float)TC);

    // ---- phase 1: chunk into registers (CACHED loads), local scan ----
    const size_t base = (size_t)c * TC * HV + t;
    float4 buf[TC];
#pragma unroll
    for (int i = 0; i < TC; ++i)
        buf[i] = xv[base + (size_t)i * HV];

    float4 s = make_float4(0.f, 0.f, 0.f, 0.f);
#pragma unroll
    for (int i = 0; i < TC; ++i) {
        s.x = fmaf(lx, s.x, buf[i].x);
        s.y = fmaf(ly, s.y, buf[i].y);
        s.z = fmaf(lz, s.z, buf[i].z);
        s.w = fmaf(lw, s.w, buf[i].w);
        buf[i] = s;
    }

    float4 cc;                           // carry into this chunk
    if (r != P - 1) {
        // ---- normal block: publish end, wait on PRIVATE carry flag ----
        ends[(size_t)c * HV + t] = s;
        __threadfence();
        __syncthreads();
        if (t == 0) {
            st_flag(&eflag[(size_t)c * FS], 1u);
            while (ld_flag(&kflag[(size_t)c * FS]) == 0u)
                __builtin_amdgcn_s_sleep(8);
        }
        __syncthreads();
        __threadfence();
        cc = kc[(size_t)c * HV + t];
    } else {
        // ---- partition rep: owns all carry math for this partition ----
        if (t < P - 1) {
            while (ld_flag(&eflag[(size_t)(c - (P - 1) + t) * FS]) == 0u)
                __builtin_amdgcn_s_sleep(2);
        }
        __syncthreads();
        __threadfence();

        const float4* ep = ends + (size_t)p * P * HV + t;

        // partition aggregate a_p (zero-entry scan through all 16 chunks)
        float4 a = make_float4(0.f, 0.f, 0.f, 0.f);
#pragma unroll
        for (int j0 = 0; j0 < P - 1; j0 += 5) {
            float4 v[5];
#pragma unroll
            for (int j = 0; j < 5; ++j)
                v[j] = ep[(size_t)(j0 + j) * HV];
#pragma unroll
            for (int j = 0; j < 5; ++j) {
                a.x = fmaf(Tx, a.x, v[j].x);
                a.y = fmaf(Ty, a.y, v[j].y);
                a.z = fmaf(Tz, a.z, v[j].z);
                a.w = fmaf(Tw, a.w, v[j].w);
            }
        }
        a.x = fmaf(Tx, a.x, s.x);
        a.y = fmaf(Ty, a.y, s.y);
        a.z = fmaf(Tz, a.z, s.z);
        a.w = fmaf(Tw, a.w, s.w);
        pagg[(size_t)p * HV + t] = a;
        __threadfence();
        __syncthreads();
        if (t == 0) st_flag(&aflag[(size_t)p * FS], 1u);

        // carry into partition start: Qc = scan(a_0..a_{p-1})
        if (t < p) {
            while (ld_flag(&aflag[(size_t)t * FS]) == 0u)
                __builtin_amdgcn_s_sleep(2);
        }
        __syncthreads();
        __threadfence();

        const float fQ = (float)(TC * P);
        const float Qx = expf(tv.x * fQ), Qy = expf(tv.y * fQ),
                    Qz = expf(tv.z * fQ), Qw = expf(tv.w * fQ);
        float4 q = make_float4(0.f, 0.f, 0.f, 0.f);
        for (int q0 = 0; q0 < p; q0 += 4) {
            float4 v[4];
#pragma unroll
            for (int j = 0; j < 4; ++j)
                if (q0 + j < p) v[j] = pagg[(size_t)(q0 + j) * HV + t];
#pragma unroll
            for (int j = 0; j < 4; ++j) {
                if (q0 + j < p) {
                    q.x = fmaf(Qx, q.x, v[j].x);
                    q.y = fmaf(Qy, q.y, v[j].y);
                    q.z = fmaf(Qz, q.z, v[j].z);
                    q.w = fmaf(Qw, q.w, v[j].w);
                }
            }
        }

        // publish per-chunk carries: K_0 = Qc; K_{j+1} = T o K_j + E_j
        float4 k = q;
#pragma unroll
        for (int j0 = 0; j0 < P - 1; j0 += 5) {
            float4 v[5];
#pragma unroll
            for (int j = 0; j < 5; ++j)
                v[j] = ep[(size_t)(j0 + j) * HV];
#pragma unroll
            for (int j = 0; j < 5; ++j) {
                kc[(size_t)(p * P + j0 + j) * HV + t] = k;
                k.x = fmaf(Tx, k.x, v[j].x);
                k.y = fmaf(Ty, k.y, v[j].y);
                k.z = fmaf(Tz, k.z, v[j].z);
                k.w = fmaf(Tw, k.w, v[j].w);
            }
        }
        __threadfence();
        __syncthreads();
        if (t < P - 1) st_flag(&kflag[(size_t)(c - (P - 1) + t) * FS], 1u);
        cc = k;                          // carry into rep's own chunk (r=15)
    }

    // ---- epilogue: apply carry, nt-store y ----
    float4 pm = make_float4(lx, ly, lz, lw);
    nt4* yn = (nt4*)yv;
#pragma unroll
    for (int i = 0; i < TC; ++i) {
        nt4 o = { fmaf(pm.x, cc.x, buf[i].x),
                  fmaf(pm.y, cc.y, buf[i].y),
                  fmaf(pm.z, cc.z, buf[i].z),
                  fmaf(pm.w, cc.w, buf[i].w) };
        __builtin_nontemporal_store(o, &yn[base + (size_t)i * HV]);
        pm.x *= lx; pm.y *= ly; pm.z *= lz; pm.w *= lw;
    }
}

// ---------------- R7 cooperative fallback ----------------

__global__ __launch_bounds__(256, 4)
void li_coop(const float4* __restrict__ xv, const float4* __restrict__ tauv,
             float4* __restrict__ yv, float4* __restrict__ ends,
             float4* __restrict__ pa, int HV, int NP)
{
    const int t = threadIdx.x;
    const int c = blockIdx.x;

    const float4 tv = tauv[t];
    const float lx = expf(tv.x), ly = expf(tv.y),
                lz = expf(tv.z), lw = expf(tv.w);
    const float Tx = expf(tv.x * (float)TC), Ty = expf(tv.y * (float)TC),
                Tz = expf(tv.z * (float)TC), Tw = expf(tv.w * (float)TC);
    const float fQ = (float)(TC * P);
    const float Qx = expf(tv.x * fQ), Qy = expf(tv.y * fQ),
                Qz = expf(tv.z * fQ), Qw = expf(tv.w * fQ);

    const size_t base = (size_t)c * TC * HV + t;
    float4 buf[TC];
#pragma unroll
    for (int i = 0; i < TC; ++i)
        buf[i] = ntload(&xv[base + (size_t)i * HV]);

    float4 s = make_float4(0.f, 0.f, 0.f, 0.f);
#pragma unroll
    for (int i = 0; i < TC; ++i) {
        s.x = fmaf(lx, s.x, buf[i].x);
        s.y = fmaf(ly, s.y, buf[i].y);
        s.z = fmaf(lz, s.z, buf[i].z);
        s.w = fmaf(lw, s.w, buf[i].w);
        buf[i] = s;
    }
    ends[(size_t)c * HV + t] = s;

    cg::this_grid().sync();

    if (c < NP) {
        const float4* ep = ends + (size_t)c * P * HV + t;
        float4 a = make_float4(0.f, 0.f, 0.f, 0.f);
#pragma unroll
        for (int j0 = 0; j0 < P; j0 += 8) {
            float4 v[8];
#pragma unroll
            for (int j = 0; j < 8; ++j)
                v[j] = ep[(size_t)(j0 + j) * HV];
#pragma unroll
            for (int j = 0; j < 8; ++j) {
                a.x = fmaf(Tx, a.x, v[j].x);
                a.y = fmaf(Ty, a.y, v[j].y);
                a.z = fmaf(Tz, a.z, v[j].z);
                a.w = fmaf(Tw, a.w, v[j].w);
            }
        }
        pa[(size_t)c * HV + t] = a;
    }

    cg::this_grid().sync();

    const int p = c / P;
    const int r = c % P;

    float4 carry = make_float4(0.f, 0.f, 0.f, 0.f);
    for (int q0 = 0; q0 < p; q0 += 8) {
        const int n = p - q0;
        float4 v[8];
#pragma unroll
        for (int j = 0; j < 8; ++j)
            if (j < n) v[j] = pa[(size_t)(q0 + j) * HV + t];
#pragma unroll
        for (int j = 0; j < 8; ++j) {
            if (j < n) {
                carry.x = fmaf(Qx, carry.x, v[j].x);
                carry.y = fmaf(Qy, carry.y, v[j].y);
                carry.z = fmaf(Qz, carry.z, v[j].z);
                carry.w = fmaf(Qw, carry.w, v[j].w);
            }
        }
    }
    {
        const float4* ep = ends + (size_t)p * P * HV + t;
        for (int j0 = 0; j0 < r; j0 += 8) {
            const int n = r - j0;
            float4 v[8];
#pragma unroll
            for (int j = 0; j < 8; ++j)
                if (j < n) v[j] = ep[(size_t)(j0 + j) * HV];
#pragma unroll
            for (int j = 0; j < 8; ++j) {
                if (j < n) {
                    carry.x = fmaf(Tx, carry.x, v[j].x);
                    carry.y = fmaf(Ty, carry.y, v[j].y);
                    carry.z = fmaf(Tz, carry.z, v[j].z);
                    carry.w = fmaf(Tw, carry.w, v[j].w);
                }
            }
        }
    }

    float4 pm = make_float4(lx, ly, lz, lw);
    nt4* yn = (nt4*)yv;
#pragma unroll
    for (int i = 0; i < TC; ++i) {
        nt4 o = { fmaf(pm.x, carry.x, buf[i].x),
                  fmaf(pm.y, carry.y, buf[i].y),
                  fmaf(pm.z, carry.z, buf[i].z),
                  fmaf(pm.w, carry.w, buf[i].w) };
        __builtin_nontemporal_store(o, &yn[base + (size_t)i * HV]);
        pm.x *= lx; pm.y *= ly; pm.z *= lz; pm.w *= lw;
    }
}

// ---------------- R6 feed-forward fallback ----------------

__global__ __launch_bounds__(256)
void li_ends(const float4* __restrict__ xv, const float4* __restrict__ tauv,
             float4* __restrict__ ends, int HV) {
    const int t = threadIdx.x;
    const int c = blockIdx.x;
    const float4 tv = tauv[t];
    const float lx = expf(tv.x), ly = expf(tv.y),
                lz = expf(tv.z), lw = expf(tv.w);
    const float4* xp = xv + (size_t)c * TC * HV + t;
    float4 buf[TC];
#pragma unroll
    for (int i = 0; i < TC; ++i)
        buf[i] = xp[(size_t)i * HV];
    float4 s = make_float4(0.f, 0.f, 0.f, 0.f);
#pragma unroll
    for (int i = 0; i < TC; ++i) {
        s.x = fmaf(lx, s.x, buf[i].x);
        s.y = fmaf(ly, s.y, buf[i].y);
        s.z = fmaf(lz, s.z, buf[i].z);
        s.w = fmaf(lw, s.w, buf[i].w);
    }
    ends[(size_t)c * HV + t] = s;
}

__global__ __launch_bounds__(256)
void li_pagg(const float4* __restrict__ ends, const float4* __restrict__ tauv,
             float4* __restrict__ pa, int HV) {
    const int gid = blockIdx.x * 256 + threadIdx.x;
    const int t = gid % HV;
    const int p = gid / HV;
    const float4 tv = tauv[t];
    const float Tx = expf(tv.x * (float)TC), Ty = expf(tv.y * (float)TC),
                Tz = expf(tv.z * (float)TC), Tw = expf(tv.w * (float)TC);
    const float4* ep = ends + (size_t)p * P * HV + t;
    float4 buf[P];
#pragma unroll
    for (int j = 0; j < P; ++j)
        buf[j] = ep[(size_t)j * HV];
    float4 s = make_float4(0.f, 0.f, 0.f, 0.f);
#pragma unroll
    for (int j = 0; j < P; ++j) {
        s.x = fmaf(Tx, s.x, buf[j].x);
        s.y = fmaf(Ty, s.y, buf[j].y);
        s.z = fmaf(Tz, s.z, buf[j].z);
        s.w = fmaf(Tw, s.w, buf[j].w);
    }
    pa[(size_t)p * HV + t] = s;
}

__global__ __launch_bounds__(256)
void li_pscan(float4* __restrict__ pa, const float4* __restrict__ tauv,
              int HV, int NP) {
    const int t = threadIdx.x;
    const float4 tv = tauv[t];
    const float fP = (float)(P * TC);
    const float Px = expf(tv.x * fP), Py = expf(tv.y * fP),
                Pz = expf(tv.z * fP), Pw = expf(tv.w * fP);
    float4 c = make_float4(0.f, 0.f, 0.f, 0.f);
    for (int p0 = 0; p0 < NP; p0 += 16) {
        float4 v[16];
#pragma unroll
        for (int j = 0; j < 16; ++j)
            v[j] = pa[(size_t)(p0 + j) * HV + t];
#pragma unroll
        for (int j = 0; j < 16; ++j) {
            const float4 a = v[j];
            v[j] = c;
            c.x = fmaf(Px, c.x, a.x);
            c.y = fmaf(Py, c.y, a.y);
            c.z = fmaf(Pz, c.z, a.z);
            c.w = fmaf(Pw, c.w, a.w);
        }
#pragma unroll
        for (int j = 0; j < 16; ++j)
            pa[(size_t)(p0 + j) * HV + t] = v[j];
    }
}

__global__ __launch_bounds__(256)
void li_out(const float4* __restrict__ xv, const float4* __restrict__ tauv,
            const float4* __restrict__ ends, const float4* __restrict__ pc,
            float4* __restrict__ yv, int HV) {
    const int t = threadIdx.x;
    const int c = blockIdx.x;
    const int p = c / P;
    const int r = c % P;
    const float4 tv = tauv[t];
    const float lx = expf(tv.x), ly = expf(tv.y),
                lz = expf(tv.z), lw = expf(tv.w);
    const float Tx = expf(tv.x * (float)TC), Ty = expf(tv.y * (float)TC),
                Tz = expf(tv.z * (float)TC), Tw = expf(tv.w * (float)TC);
    float4 carry = pc[(size_t)p * HV + t];
    {
        float4 v[P - 1];
        const float4* ep = ends + (size_t)p * P * HV + t;
#pragma unroll
        for (int j = 0; j < P - 1; ++j)
            if (j < r) v[j] = ep[(size_t)j * HV];
#pragma unroll
        for (int j = 0; j < P - 1; ++j) {
            if (j < r) {
                carry.x = fmaf(Tx, carry.x, v[j].x);
                carry.y = fmaf(Ty, carry.y, v[j].y);
                carry.z = fmaf(Tz, carry.z, v[j].z);
                carry.w = fmaf(Tw, carry.w, v[j].w);
            }
        }
    }
    const size_t base = (size_t)c * TC * HV + t;
    float4 buf[TC];
#pragma unroll
    for (int i = 0; i < TC; ++i)
        buf[i] = xv[base + (size_t)i * HV];
    float4 s = carry;
#pragma unroll
    for (int i = 0; i < TC; ++i) {
        s.x = fmaf(lx, s.x, buf[i].x);
        s.y = fmaf(ly, s.y, buf[i].y);
        s.z = fmaf(lz, s.z, buf[i].z);
        s.w = fmaf(lw, s.w, buf[i].w);
        buf[i] = s;
    }
    nt4* yn = (nt4*)yv;
#pragma unroll
    for (int i = 0; i < TC; ++i) {
        nt4 o = { buf[i].x, buf[i].y, buf[i].z, buf[i].w };
        __builtin_nontemporal_store(o, &yn[base + (size_t)i * HV]);
    }
}

extern "C" void kernel_launch(void* const* d_in, const int* in_sizes, int n_in,
                              void* d_out, int out_size, void* d_ws, size_t ws_size,
                              hipStream_t stream) {
    const float* x   = (const float*)d_in[0];
    const float* tau = (const float*)d_in[1];
    float* y = (float*)d_out;

    const int H  = in_sizes[1];        // 1024
    const int L  = in_sizes[0] / H;    // 16384
    const int C  = L / TC;             // 1024
    const int NP = C / P;              // 64
    const int HV = H / 4;              // 256 float4 columns

    float4* ends = (float4*)d_ws;                       // C*HV  float4 = 4 MB
    float4* pagg = ends + (size_t)C * HV;               // NP*HV float4 = 256 KB
    float4* kc   = pagg + (size_t)NP * HV;              // C*HV  float4 = 4 MB
    unsigned* eflag = (unsigned*)(kc + (size_t)C * HV);
    unsigned* aflag = eflag + (size_t)C * FS;
    unsigned* kflag = aflag + (size_t)NP * FS;
    const size_t flagBytes = (size_t)(2 * C + NP) * FS * sizeof(unsigned);
    const size_t needLB = ((size_t)2 * C * HV + (size_t)NP * HV) * sizeof(float4)
                          + flagBytes;                  // ~8.5 MB

    const float4* xv   = (const float4*)x;
    const float4* tauv = (const float4*)tau;
    float4*       yv   = (float4*)y;

    // Cached device/occupancy queries (host-side, graph-capture safe).
    static int lb_bpc = -1;
    static int nCU    = -1;
    if (lb_bpc < 0) {
        int b = 0;
        if (hipOccupancyMaxActiveBlocksPerMultiprocessor(&b, li_rep, 256, 0)
            != hipSuccess) b = 0;
        lb_bpc = b;
        hipDeviceProp_t prop;
        int dev = 0;
        if (hipGetDevice(&dev) == hipSuccess &&
            hipGetDeviceProperties(&prop, dev) == hipSuccess)
            nCU = prop.multiProcessorCount;
        else
            nCU = 0;
    }

    // Lookback path requires full co-residency so spins can't deadlock
    // (normal blocks wait on their partition rep, which has a higher id).
    if (lb_bpc >= 4 && (size_t)lb_bpc * (size_t)nCU >= (size_t)C &&
        ws_size >= needLB) {
        hipMemsetAsync(eflag, 0, flagBytes, stream);
        li_rep<<<dim3(C), dim3(256), 0, stream>>>(
            xv, tauv, yv, ends, pagg, kc, eflag, aflag, kflag, HV);
        return;
    }

    // R7 cooperative fallback.
    int blocksPerCU = 0;
    hipError_t qe = hipOccupancyMaxActiveBlocksPerMultiprocessor(
        &blocksPerCU, li_coop, 256, 0);
    bool coop_ok = false;
    if (qe == hipSuccess && blocksPerCU >= 4) {
        void* args[] = { (void*)&xv, (void*)&tauv, (void*)&yv,
                         (void*)&ends, (void*)&pagg, (void*)&HV, (void*)&NP };
        hipError_t le = hipLaunchCooperativeKernel(
            li_coop, dim3(C), dim3(256), args, 0u, stream);
        coop_ok = (le == hipSuccess);
    }

    if (!coop_ok) {
        li_ends <<<dim3(C),             dim3(256), 0, stream>>>(xv, tauv, ends, HV);
        li_pagg <<<dim3(NP * HV / 256), dim3(256), 0, stream>>>(ends, tauv, pagg, HV);
        li_pscan<<<dim3(1),             dim3(256), 0, stream>>>(pagg, tauv, HV, NP);
        li_out  <<<dim3(C),             dim3(256), 0, stream>>>(xv, tauv, ends, pagg,
                                                                yv, HV);
    }
}

// Round 3
// 115.459 us; speedup vs baseline: 1.1494x; 1.1445x over previous
//
#include <hip/hip_runtime.h>
#include <cmath>

// Diagonal linear recurrence y[l][h] = exp(tau[h])*y[l-1][h] + x[l][h]
// L=16384, H=1024, fp32.
//
// R10: windowed scan, ZERO inter-block communication.
// Evidence: R6 (4-kernel), R7 (grid.sync), R8 (flag lookback), R9
// (rep lookback) -- four disjoint sync structures, identical 132us live.
// The one shared ingredient besides the harness: a globally-ordered carry
// exchange with device-scope fences across 8 non-coherent XCD L2s.
// R10 removes inter-block coupling entirely: lambda = exp(tau) decays
// (bench: 0.8^64 = 6.3e-7, x state std ~1.7, max ~10 -> truncation error
// <1e-5, four orders below the passing absmax 0.03125). Each block owns
// BR=64 output rows and rebuilds its carry from a W=64-row warm-up window
// with zero initial state. Single kernel, no workspace, no flags, no
// fences, no co-residency requirement.
// Correctness net for arbitrary tau: if any channel in the thread's float4
// has tau*W > -13.8 (decay not negligible), that thread first walks the
// exact prefix [0, warm_start) serially. Never taken on bench data.
// Fallback for non-conforming shapes: R6 feed-forward 4-kernel path.

static constexpr int BR = 64;    // output rows per block  -> 256 blocks
static constexpr int W  = 64;    // warm-up rows (0.8^64 = 6.3e-7)
static constexpr int TC = 16;    // fallback path: rows per chunk
static constexpr int P  = 16;    // fallback path: chunks per partition

typedef float nt4 __attribute__((ext_vector_type(4)));

__global__ __launch_bounds__(256, 1)   // 4 waves/block, 1 block/CU; free regs
void li_win(const float4* __restrict__ xv, const float4* __restrict__ tauv,
            float4* __restrict__ yv, int HV)
{
    const int t = threadIdx.x;           // float4 column (4 channels)
    const int c = blockIdx.x;            // row segment
    const int r0 = c * BR;               // first output row

    const float4 tv = tauv[t];
    const float lx = expf(tv.x), ly = expf(tv.y),
                lz = expf(tv.z), lw = expf(tv.w);

    float4 s = make_float4(0.f, 0.f, 0.f, 0.f);

    if (c > 0) {
        const int rw = r0 - W;           // warm-up start row (>=0)

        // Safety net: if decay over W rows is not negligible for every
        // channel this thread owns, walk the exact prefix [0, rw) first.
        // exp(-13.8) = 1e-6; bench tau*W = -14.28 -> fast path.
        const float mt = fmaxf(fmaxf(tv.x, tv.y), fmaxf(tv.z, tv.w));
        if (mt * (float)W > -13.8f) {
            const float4* xp0 = xv + t;
            for (int rr = 0; rr < rw; ++rr) {
                const float4 v = xp0[(size_t)rr * HV];
                s.x = fmaf(lx, s.x, v.x);
                s.y = fmaf(ly, s.y, v.y);
                s.z = fmaf(lz, s.z, v.z);
                s.w = fmaf(lw, s.w, v.w);
            }
        }

        // Warm-up window: rows [rw, r0), no stores. Loads are independent;
        // full unroll lets the compiler hoist deep (MLP >> latency need).
        const float4* xp = xv + (size_t)rw * HV + t;
#pragma unroll
        for (int i = 0; i < W; ++i) {
            const float4 v = xp[(size_t)i * HV];
            s.x = fmaf(lx, s.x, v.x);
            s.y = fmaf(ly, s.y, v.y);
            s.z = fmaf(lz, s.z, v.z);
            s.w = fmaf(lw, s.w, v.w);
        }
    }

    // Main segment: rows [r0, r0+BR), scan + nontemporal store.
    const float4* xp = xv + (size_t)r0 * HV + t;
    nt4* yp = (nt4*)yv + (size_t)r0 * HV + t;
#pragma unroll
    for (int i = 0; i < BR; ++i) {
        const float4 v = xp[(size_t)i * HV];
        s.x = fmaf(lx, s.x, v.x);
        s.y = fmaf(ly, s.y, v.y);
        s.z = fmaf(lz, s.z, v.z);
        s.w = fmaf(lw, s.w, v.w);
        nt4 o = { s.x, s.y, s.z, s.w };
        __builtin_nontemporal_store(o, &yp[(size_t)i * HV]);
    }
}

// ---------------- R6 feed-forward fallback (general shapes) ----------------

__global__ __launch_bounds__(256)
void li_ends(const float4* __restrict__ xv, const float4* __restrict__ tauv,
             float4* __restrict__ ends, int HV) {
    const int t = threadIdx.x;
    const int c = blockIdx.x;
    const float4 tv = tauv[t];
    const float lx = expf(tv.x), ly = expf(tv.y),
                lz = expf(tv.z), lw = expf(tv.w);
    const float4* xp = xv + (size_t)c * TC * HV + t;
    float4 buf[TC];
#pragma unroll
    for (int i = 0; i < TC; ++i)
        buf[i] = xp[(size_t)i * HV];
    float4 s = make_float4(0.f, 0.f, 0.f, 0.f);
#pragma unroll
    for (int i = 0; i < TC; ++i) {
        s.x = fmaf(lx, s.x, buf[i].x);
        s.y = fmaf(ly, s.y, buf[i].y);
        s.z = fmaf(lz, s.z, buf[i].z);
        s.w = fmaf(lw, s.w, buf[i].w);
    }
    ends[(size_t)c * HV + t] = s;
}

__global__ __launch_bounds__(256)
void li_pagg(const float4* __restrict__ ends, const float4* __restrict__ tauv,
             float4* __restrict__ pa, int HV) {
    const int gid = blockIdx.x * 256 + threadIdx.x;
    const int t = gid % HV;
    const int p = gid / HV;
    const float4 tv = tauv[t];
    const float Tx = expf(tv.x * (float)TC), Ty = expf(tv.y * (float)TC),
                Tz = expf(tv.z * (float)TC), Tw = expf(tv.w * (float)TC);
    const float4* ep = ends + (size_t)p * P * HV + t;
    float4 buf[P];
#pragma unroll
    for (int j = 0; j < P; ++j)
        buf[j] = ep[(size_t)j * HV];
    float4 s = make_float4(0.f, 0.f, 0.f, 0.f);
#pragma unroll
    for (int j = 0; j < P; ++j) {
        s.x = fmaf(Tx, s.x, buf[j].x);
        s.y = fmaf(Ty, s.y, buf[j].y);
        s.z = fmaf(Tz, s.z, buf[j].z);
        s.w = fmaf(Tw, s.w, buf[j].w);
    }
    pa[(size_t)p * HV + t] = s;
}

__global__ __launch_bounds__(256)
void li_pscan(float4* __restrict__ pa, const float4* __restrict__ tauv,
              int HV, int NP) {
    const int t = threadIdx.x;
    const float4 tv = tauv[t];
    const float fP = (float)(P * TC);
    const float Px = expf(tv.x * fP), Py = expf(tv.y * fP),
                Pz = expf(tv.z * fP), Pw = expf(tv.w * fP);
    float4 c = make_float4(0.f, 0.f, 0.f, 0.f);
    for (int p0 = 0; p0 < NP; p0 += 16) {
        float4 v[16];
#pragma unroll
        for (int j = 0; j < 16; ++j)
            v[j] = pa[(size_t)(p0 + j) * HV + t];
#pragma unroll
        for (int j = 0; j < 16; ++j) {
            const float4 a = v[j];
            v[j] = c;
            c.x = fmaf(Px, c.x, a.x);
            c.y = fmaf(Py, c.y, a.y);
            c.z = fmaf(Pz, c.z, a.z);
            c.w = fmaf(Pw, c.w, a.w);
        }
#pragma unroll
        for (int j = 0; j < 16; ++j)
            pa[(size_t)(p0 + j) * HV + t] = v[j];
    }
}

__global__ __launch_bounds__(256)
void li_out(const float4* __restrict__ xv, const float4* __restrict__ tauv,
            const float4* __restrict__ ends, const float4* __restrict__ pc,
            float4* __restrict__ yv, int HV) {
    const int t = threadIdx.x;
    const int c = blockIdx.x;
    const int p = c / P;
    const int r = c % P;
    const float4 tv = tauv[t];
    const float lx = expf(tv.x), ly = expf(tv.y),
                lz = expf(tv.z), lw = expf(tv.w);
    const float Tx = expf(tv.x * (float)TC), Ty = expf(tv.y * (float)TC),
                Tz = expf(tv.z * (float)TC), Tw = expf(tv.w * (float)TC);
    float4 carry = pc[(size_t)p * HV + t];
    {
        float4 v[P - 1];
        const float4* ep = ends + (size_t)p * P * HV + t;
#pragma unroll
        for (int j = 0; j < P - 1; ++j)
            if (j < r) v[j] = ep[(size_t)j * HV];
#pragma unroll
        for (int j = 0; j < P - 1; ++j) {
            if (j < r) {
                carry.x = fmaf(Tx, carry.x, v[j].x);
                carry.y = fmaf(Ty, carry.y, v[j].y);
                carry.z = fmaf(Tz, carry.z, v[j].z);
                carry.w = fmaf(Tw, carry.w, v[j].w);
            }
        }
    }
    const size_t base = (size_t)c * TC * HV + t;
    float4 buf[TC];
#pragma unroll
    for (int i = 0; i < TC; ++i)
        buf[i] = xv[base + (size_t)i * HV];
    float4 s = carry;
#pragma unroll
    for (int i = 0; i < TC; ++i) {
        s.x = fmaf(lx, s.x, buf[i].x);
        s.y = fmaf(ly, s.y, buf[i].y);
        s.z = fmaf(lz, s.z, buf[i].z);
        s.w = fmaf(lw, s.w, buf[i].w);
        buf[i] = s;
    }
    nt4* yn = (nt4*)yv;
#pragma unroll
    for (int i = 0; i < TC; ++i) {
        nt4 o = { buf[i].x, buf[i].y, buf[i].z, buf[i].w };
        __builtin_nontemporal_store(o, &yn[base + (size_t)i * HV]);
    }
}

extern "C" void kernel_launch(void* const* d_in, const int* in_sizes, int n_in,
                              void* d_out, int out_size, void* d_ws, size_t ws_size,
                              hipStream_t stream) {
    const float* x   = (const float*)d_in[0];
    const float* tau = (const float*)d_in[1];
    float* y = (float*)d_out;

    const int H  = in_sizes[1];        // 1024
    const int L  = in_sizes[0] / H;    // 16384
    const int HV = H / 4;              // 256 float4 columns

    const float4* xv   = (const float4*)x;
    const float4* tauv = (const float4*)tau;
    float4*       yv   = (float4*)y;

    // Windowed path: needs HV==256 (one thread per float4 column) and
    // L divisible by BR. Bench shape satisfies both.
    if (HV == 256 && (L % BR) == 0 && (H % 4) == 0) {
        li_win<<<dim3(L / BR), dim3(256), 0, stream>>>(xv, tauv, yv, HV);
        return;
    }

    // General-shape fallback: R6 feed-forward 4-kernel path.
    const int C  = L / TC;
    const int NP = C / P;
    float4* ends = (float4*)d_ws;                       // C*HV float4
    float4* pa   = ends + (size_t)C * HV;               // NP*HV float4

    li_ends <<<dim3(C),             dim3(256), 0, stream>>>(xv, tauv, ends, HV);
    li_pagg <<<dim3(NP * HV / 256), dim3(256), 0, stream>>>(ends, tauv, pa, HV);
    li_pscan<<<dim3(1),             dim3(256), 0, stream>>>(pa, tauv, HV, NP);
    li_out  <<<dim3(C),             dim3(256), 0, stream>>>(xv, tauv, ends, pa,
                                                            yv, HV);
}